// Round 7
// baseline (517.974 us; speedup 1.0000x reference)
//
#include <hip/hip_runtime.h>
#include <hip/hip_cooperative_groups.h>

namespace cg = cooperative_groups;

#define B_ 128   // batch

typedef __attribute__((ext_vector_type(4))) float f4;
typedef __attribute__((ext_vector_type(2))) float f2;

struct Params {
  const float* sample1;
  const float* Tr; const float* Ti;
  const float* W1; const float* b1;
  const float* W2; const float* b2;
  const float* W3; const float* b3;
  const float* W4; const float* b4;
  const float* W5; const float* b5;
  float* Pa; float* Pb; float* P5; float* cc; float* out;
};

// ---- generic split-K MLP phase: P[zz][b][j] = sum_{k in slice zz} act[b,k]*W[k,j]
// virtual grid NVB = NCH*16*NZZ, 256-col chunks, BG=8 rows, k-major LDS.
template<int NSUM, int NCH, int NZZ, int KS, int N_T, int KTOT>
__device__ __forceinline__ void mlp_phase(float* smem,
    const float* __restrict__ A, const float* __restrict__ bias_in,
    const float* __restrict__ W, float* __restrict__ P) {
  constexpr int BG = 8;
  constexpr int NVB = NCH * 16 * NZZ;
  const int tid = threadIdx.x;
  for (int vb = blockIdx.x; vb < NVB; vb += gridDim.x) {
    // XCD affinity heuristic: zz % 8 == vb & 7.
    const int xcd = vb & 7;
    const int idx = vb >> 3;
    const int nch = idx % NCH;
    const int t2  = idx / NCH;
    const int yy  = t2 & 15;
    const int zhi = t2 >> 4;
    const int zz  = xcd + 8 * zhi;
    const int b0  = yy * BG;
    const int k0  = zz * KS;
    const int klen = (NSUM == 0) ? min(KTOT - k0, KS) : KS;
    float (*sA)[BG] = (float (*)[BG])smem;

    __syncthreads();   // protect smem reuse across vb iterations
    if (NSUM == 0) {
      for (int g = 0; g < BG; ++g)
        for (int k = tid; k < klen; k += 256)
          sA[k][g] = A[(size_t)(b0 + g) * KTOT + k0 + k];
    } else {
      constexpr int K4 = KS / 4;
      for (int i2 = tid; i2 < BG * K4; i2 += 256) {
        int g = i2 / K4, k4 = i2 % K4;
        f4 v = *(const f4*)(bias_in + k0 + 4 * k4);
        for (int s = 0; s < NSUM; ++s)
          v += *(const f4*)(A + ((size_t)s * B_ + b0 + g) * KTOT + k0 + 4 * k4);
        v.x = fmaxf(v.x, 0.f); v.y = fmaxf(v.y, 0.f);
        v.z = fmaxf(v.z, 0.f); v.w = fmaxf(v.w, 0.f);
        sA[4 * k4 + 0][g] = v.x; sA[4 * k4 + 1][g] = v.y;
        sA[4 * k4 + 2][g] = v.z; sA[4 * k4 + 3][g] = v.w;
      }
    }
    __syncthreads();

    const int cg_ = tid & 63;   // 64 f4 col-groups = 256 cols
    const int rg  = tid >> 6;   // 4 row-groups x 2 rows
    f4 acc0 = (f4)0.f, acc1 = (f4)0.f;
    const float* wp = W + (size_t)k0 * N_T + nch * 256 + 4 * cg_;
#pragma unroll 8
    for (int k = 0; k < klen; ++k) {
      f4 w = *(const f4*)wp; wp += N_T;
      f2 a = *(const f2*)&sA[k][rg * 2];   // broadcast ds_read_b64
      acc0 += a.x * w;
      acc1 += a.y * w;
    }
    float* pp = P + ((size_t)zz * B_ + b0 + rg * 2) * N_T + nch * 256 + 4 * cg_;
    *(f4*)pp = acc0;
    *(f4*)(pp + N_T) = acc1;
  }
}

// ---- layer 5: N=264, K=512, NSUM=16, SPLITK=4; virtual grid 64 ----
__device__ __forceinline__ void l5_phase(float* smem,
    const float* __restrict__ Pprev, const float* __restrict__ bias_in,
    const float* __restrict__ W5, float* __restrict__ P5) {
  const int tid = threadIdx.x;
  for (int vb = blockIdx.x; vb < 64; vb += gridDim.x) {
    const int yy = vb & 15, zzz = vb >> 4;
    const int b0 = yy * 8, k0 = zzz * 128;
    float (*sA)[128] = (float (*)[128])smem;
    __syncthreads();
    {
      int g = tid >> 5, k4 = tid & 31;
      f4 v = *(const f4*)(bias_in + k0 + 4 * k4);
      for (int s = 0; s < 16; ++s)
        v += *(const f4*)(Pprev + ((size_t)s * B_ + b0 + g) * 512 + k0 + 4 * k4);
      v.x = fmaxf(v.x, 0.f); v.y = fmaxf(v.y, 0.f);
      v.z = fmaxf(v.z, 0.f); v.w = fmaxf(v.w, 0.f);
      *(f4*)&sA[g][4 * k4] = v;
    }
    __syncthreads();
    if (tid < 132) {
      f2 acc[8];
#pragma unroll
      for (int r = 0; r < 8; ++r) acc[r] = (f2)0.f;
      const float* wp = W5 + (size_t)k0 * 264 + 2 * tid;
#pragma unroll 4
      for (int k = 0; k < 128; ++k) {
        f2 w = *(const f2*)wp;
        wp += 264;
#pragma unroll
        for (int r = 0; r < 8; ++r) acc[r] += sA[r][k] * w;
      }
#pragma unroll
      for (int r = 0; r < 8; ++r)
        *(f2*)(P5 + ((size_t)zzz * B_ + b0 + r) * 264 + 2 * tid) = acc[r];
    }
  }
}

// ---- ccc: virtual blocks 0..1023, each handles 8 consecutive (b,c) pairs ----
__device__ __forceinline__ void ccc_phase(float* smem,
    const float* __restrict__ Tr, const float* __restrict__ Ti,
    const float* __restrict__ P5, const float* __restrict__ b5,
    float* __restrict__ cc) {
  float* sx = smem;          // 104 floats
  float* sy = smem + 104;
  __shared__ float sred[4];
  const int tid = threadIdx.x;

  for (int vb = blockIdx.x; vb < 1024; vb += gridDim.x) {
    const int bc0 = vb * 8;
    const int b   = bc0 >> 6;

    __syncthreads();   // protect sx/sy reuse across vb iterations
    if (tid < 100) {
      float tr = b5[tid], ti = b5[100 + tid];
#pragma unroll
      for (int s = 0; s < 4; ++s) {
        tr += P5[(size_t)s * B_ * 264 + b * 264 + tid];
        ti += P5[(size_t)s * B_ * 264 + b * 264 + 100 + tid];
      }
      float inv = rsqrtf(fmaf(tr, tr, ti * ti));
      sx[tid] = tr * inv;
      sy[tid] = ti * inv;
    }
    __syncthreads();

    for (int q = 0; q < 8; ++q) {
      const int bc = bc0 + q;
      const f4* Tr4 = reinterpret_cast<const f4*>(Tr + (size_t)bc * 10000);
      const f4* Ti4 = reinterpret_cast<const f4*>(Ti + (size_t)bc * 10000);

      float a0 = 0.f, a1 = 0.f, a2 = 0.f, a3 = 0.f;
#pragma unroll 4
      for (int i = tid; i < 2500; i += 256) {
        f4 t = __builtin_nontemporal_load(Tr4 + i);
        f4 u = __builtin_nontemporal_load(Ti4 + i);
        int n  = i / 25;
        int m0 = (i - n * 25) * 4;
        float xn = sx[n], yn = sy[n];
        float4 xm = *reinterpret_cast<const float4*>(&sx[m0]);
        float4 ym = *reinterpret_cast<const float4*>(&sy[m0]);
        a0 = fmaf(t.x, fmaf(xn, xm.x, yn * ym.x), a0);
        a1 = fmaf(u.x, fmaf(yn, xm.x, -(xn * ym.x)), a1);
        a2 = fmaf(t.y, fmaf(xn, xm.y, yn * ym.y), a2);
        a3 = fmaf(u.y, fmaf(yn, xm.y, -(xn * ym.y)), a3);
        a0 = fmaf(t.z, fmaf(xn, xm.z, yn * ym.z), a0);
        a1 = fmaf(u.z, fmaf(yn, xm.z, -(xn * ym.z)), a1);
        a2 = fmaf(t.w, fmaf(xn, xm.w, yn * ym.w), a2);
        a3 = fmaf(u.w, fmaf(yn, xm.w, -(xn * ym.w)), a3);
      }
      float acc = (a0 + a1) + (a2 + a3);

      for (int off = 32; off; off >>= 1) acc += __shfl_down(acc, off);
      if ((tid & 63) == 0) sred[tid >> 6] = acc;
      __syncthreads();
      if (tid == 0) cc[bc] = (sred[0] + sred[1]) + (sred[2] + sred[3]);
      __syncthreads();
    }
  }
}

// ---- finalize: virtual blocks 0..127, one b each ----
__device__ __forceinline__ void finalize_phase(float* smem,
    const float* __restrict__ P5, const float* __restrict__ b5,
    const float* __restrict__ cc, float* __restrict__ out) {
  const int tid = threadIdx.x;
  float* s_t1 = smem;          // 264
  __shared__ float s_scale;

  for (int b = blockIdx.x; b < B_; b += gridDim.x) {
    __syncthreads();
    for (int j = tid; j < 264; j += 256) {
      float v = b5[j];
#pragma unroll
      for (int s = 0; s < 4; ++s)
        v += P5[(size_t)s * B_ * 264 + b * 264 + j];
      s_t1[j] = v;
    }
    if (tid < 64) {
      float v = cc[b * 64 + tid];
      for (int off = 32; off; off >>= 1) v = fmaxf(v, __shfl_down(v, off));
      if (tid == 0) s_scale = sqrtf(1e-15f / v);
    }
    __syncthreads();

    const float scale = s_scale;
    for (int j = tid; j < 264; j += 256) {
      float o;
      if (j < 200) {
        int n = (j < 100) ? j : (j - 100);
        float tr = s_t1[n];
        float ti = s_t1[100 + n];
        float inv = rsqrtf(fmaf(tr, tr, ti * ti));
        o = ((j < 100) ? tr : ti) * inv * scale;
      } else {
        o = s_t1[j];
      }
      out[b * 264 + j] = o;
    }
  }
}

// ---- the mega-kernel: cooperative, grid-size-agnostic ----
__global__ __launch_bounds__(256, 4) void fused_kernel(Params p) {
  __shared__ __align__(16) float smem[1040];
  cg::grid_group grid = cg::this_grid();

  mlp_phase<0, 4, 8, 40, 1024, 303>(smem, p.sample1, nullptr, p.W1, p.Pa);
  grid.sync();
  mlp_phase<8, 4, 16, 64, 1024, 1024>(smem, p.Pa, p.b1, p.W2, p.Pb);
  grid.sync();
  mlp_phase<16, 4, 16, 64, 1024, 1024>(smem, p.Pb, p.b2, p.W3, p.Pa);
  grid.sync();
  mlp_phase<16, 2, 16, 64, 512, 1024>(smem, p.Pa, p.b3, p.W4, p.Pb);
  grid.sync();
  l5_phase(smem, p.Pb, p.b4, p.W5, p.P5);
  grid.sync();
  ccc_phase(smem, p.Tr, p.Ti, p.P5, p.b5, p.cc);
  grid.sync();
  finalize_phase(smem, p.P5, p.b5, p.cc, p.out);
}

extern "C" void kernel_launch(void* const* d_in, const int* in_sizes, int n_in,
                              void* d_out, int out_size, void* d_ws, size_t ws_size,
                              hipStream_t stream) {
  Params p;
  p.sample1 = (const float*)d_in[0];
  p.Tr = (const float*)d_in[2]; p.Ti = (const float*)d_in[3];
  p.W1 = (const float*)d_in[4];  p.b1 = (const float*)d_in[5];
  p.W2 = (const float*)d_in[6];  p.b2 = (const float*)d_in[7];
  p.W3 = (const float*)d_in[8];  p.b3 = (const float*)d_in[9];
  p.W4 = (const float*)d_in[10]; p.b4 = (const float*)d_in[11];
  p.W5 = (const float*)d_in[12]; p.b5 = (const float*)d_in[13];

  float* ws = (float*)d_ws;
  p.Pa = ws;
  p.Pb = p.Pa + 16 * B_ * 1024;
  p.P5 = p.Pb + 16 * B_ * 1024;
  p.cc = p.P5 + 4 * B_ * 264;
  p.out = (float*)d_out;

  // Clamp grid to guaranteed co-residency (cooperative launch requirement).
  int occ = 0;
  if (hipOccupancyMaxActiveBlocksPerMultiprocessor(&occ, fused_kernel, 256, 0)
          != hipSuccess || occ < 1)
    occ = 1;
  int grid = occ * 256;          // 256 CUs on MI355X
  if (grid > 1024) grid = 1024;  // phases never need more virtual blocks than 1024

  void* args[] = { (void*)&p };
  hipLaunchCooperativeKernel((const void*)fused_kernel,
                             dim3(grid), dim3(256), args, 0, stream);
}